// Round 2
// 77.614 us; speedup vs baseline: 1.0356x; 1.0356x over previous
//
#include <hip/hip_runtime.h>
#include <math.h>

// Problem constants (fixed by the reference).
#define BB 4
#define SS 2048
#define DD 16
#define HH 16
#define NM 32  // Taylor moments m = 0..31

#define EXP2(x) __builtin_amdgcn_exp2f(x)
#define LOG2E 1.44269504088896340736f

__constant__ float INVFACT[NM] = {
    1.000000000e+00f, 1.000000000e+00f, 5.000000000e-01f, 1.666666667e-01f,
    4.166666667e-02f, 8.333333333e-03f, 1.388888889e-03f, 1.984126984e-04f,
    2.480158730e-05f, 2.755731922e-06f, 2.755731922e-07f, 2.505210839e-08f,
    2.087675699e-09f, 1.605904384e-10f, 1.147074560e-11f, 7.647163732e-13f,
    4.779477332e-14f, 2.811457254e-15f, 1.561920697e-16f, 8.220635247e-18f,
    4.110317623e-19f, 1.957294106e-20f, 8.896791392e-22f, 3.868170171e-23f,
    1.611737571e-24f, 6.446950284e-26f, 2.479596263e-27f, 9.183689864e-29f,
    3.279889237e-30f, 1.130996289e-31f, 3.769987629e-33f, 1.216125042e-34f};

#define UNPACK16(X4, XR)                                                   \
  const float4 x0_ = (X4)[0], x1_ = (X4)[1], x2_ = (X4)[2], x3_ = (X4)[3]; \
  const float XR[16] = {x0_.x, x0_.y, x0_.z, x0_.w, x1_.x, x1_.y, x1_.z,   \
                        x1_.w, x2_.x, x2_.y, x2_.z, x2_.w, x3_.x, x3_.y,   \
                        x3_.z, x3_.w};

// ---------------------------------------------------------------------------
// Fused kernel: one block per (b,h), 1024 threads (16 waves).
// Stage 1: q/k/v for all 2048 rows -> LDS (24 KB).
// Stage 2: moment table SP[jb][m] = (sum_j k^m / m!, sum_j k^m v / m!)
//          for the 64 j's of block jb; thread = (jb = t>>5, m = t&31).
// Stage 3: Hillis-Steele inclusive scan of SP over jb (5 steps, in LDS).
//          Replaces the old per-query 31-iteration global prefix loop.
// Stage 4: per query i: 32-term polynomial from SP[qb-1] (wave-uniform
//          broadcast reads) + exact exp2 diagonal block from LDS.
// No MT global round-trip, no second launch for attention.
// ---------------------------------------------------------------------------
__global__ __launch_bounds__(1024) void fused_attn_kernel(
    const float* __restrict__ x, const float* __restrict__ w_qkv,
    const float* __restrict__ b_qkv, float* __restrict__ AO) {
  __shared__ float kl[SS];
  __shared__ float vl[SS];
  __shared__ float ql[SS];
  __shared__ float2 SP[32 * 32];  // [jb][m], scanned inclusively over jb

  const int bh = blockIdx.x;
  const int b = bh >> 4, h = bh & 15;
  const int t = threadIdx.x;

  // Stage 1: q, k, v for rows t and t+1024. Weights are block-uniform ->
  // scalar loads.
  {
    float wq[16], wk[16], wv[16];
#pragma unroll
    for (int i = 0; i < 16; ++i) {
      wq[i] = w_qkv[i * 48 + h];
      wk[i] = w_qkv[i * 48 + 16 + h];
      wv[i] = w_qkv[i * 48 + 32 + h];
    }
    const float bq = b_qkv[h], bk = b_qkv[16 + h], bv = b_qkv[32 + h];
#pragma unroll
    for (int rr = 0; rr < 2; ++rr) {
      const int j = rr * 1024 + t;
      const float4* X4 = (const float4*)(x + ((size_t)b * SS + j) * DD);
      UNPACK16(X4, xr);
      float qq = bq, kk = bk, vv = bv;
#pragma unroll
      for (int i = 0; i < 16; ++i) {
        qq = fmaf(xr[i], wq[i], qq);
        kk = fmaf(xr[i], wk[i], kk);
        vv = fmaf(xr[i], wv[i], vv);
      }
      ql[j] = qq;
      kl[j] = kk;
      vl[j] = vv;
    }
  }
  __syncthreads();

  // Stage 2: moments. k^m via exp-by-squaring with per-lane bit selects.
  {
    const int m = t & 31;
    const int jb = t >> 5;
    const float c = INVFACT[m];
    float s = 0.f, tv = 0.f;
    const int base = jb * 64;
    for (int u = 0; u < 64; ++u) {
      const float k = kl[base + u];  // 2-way broadcast (free)
      const float v = vl[base + u];
      const float k2 = k * k, k4 = k2 * k2, k8 = k4 * k4, k16 = k8 * k8;
      float p = (m & 1) ? k : 1.f;
      p *= (m & 2) ? k2 : 1.f;
      p *= (m & 4) ? k4 : 1.f;
      p *= (m & 8) ? k8 : 1.f;
      p *= (m & 16) ? k16 : 1.f;
      s += p;
      tv = fmaf(p, v, tv);
    }
    SP[t] = make_float2(s * c, tv * c);
  }
  __syncthreads();

  // Stage 3: inclusive scan over jb (5 Hillis-Steele steps).
  {
    const int jb = t >> 5;
#pragma unroll
    for (int off = 1; off < 32; off <<= 1) {
      const float2 self = SP[t];
      float2 othr = make_float2(0.f, 0.f);
      if (jb >= off) othr = SP[t - off * 32];
      __syncthreads();
      SP[t] = make_float2(self.x + othr.x, self.y + othr.y);
      __syncthreads();
    }
  }

  // Stage 4: attention for queries t and t+1024. Each wave covers exactly
  // one q-block -> SP row and diagonal kl/vl reads are wave-uniform
  // broadcasts; no divergence on the qb>0 branch.
  for (int rr = 0; rr < 2; ++rr) {
    const int i = rr * 1024 + t;
    const int lane = i & 63;
    const int qb = i >> 6;
    const float q = ql[i];
    const float qs = q * LOG2E;

    float num = 0.f, den = 0.f;
    if (qb > 0) {
      const float2* bc2 = SP + (size_t)(qb - 1) * 32;
      float p = 1.f;  // q^m
#pragma unroll
      for (int m = 0; m < NM; ++m) {
        const float2 st = bc2[m];  // broadcast read
        den = fmaf(p, st.x, den);
        num = fmaf(p, st.y, num);
        p *= q;
      }
    }

    // Exact diagonal block (lane-predicated: j_local <= lane).
    float ld = 0.f, ad = 0.f;
    const float4* kd4 = (const float4*)(kl + qb * 64);
    const float4* vd4 = (const float4*)(vl + qb * 64);
#pragma unroll
    for (int g = 0; g < 16; ++g) {
      const float4 k4 = kd4[g], v4 = vd4[g];
      const int jj = 4 * g;
      float e;
      e = EXP2(qs * k4.x); e = (jj + 0 <= lane) ? e : 0.f; ld += e; ad = fmaf(e, v4.x, ad);
      e = EXP2(qs * k4.y); e = (jj + 1 <= lane) ? e : 0.f; ld += e; ad = fmaf(e, v4.y, ad);
      e = EXP2(qs * k4.z); e = (jj + 2 <= lane) ? e : 0.f; ld += e; ad = fmaf(e, v4.z, ad);
      e = EXP2(qs * k4.w); e = (jj + 3 <= lane) ? e : 0.f; ld += e; ad = fmaf(e, v4.w, ad);
    }

    AO[(size_t)bh * SS + i] = (ad + num) / (ld + den);  // coalesced
  }
}

// ---------------------------------------------------------------------------
// Kernel C: out = AO @ w_out + b_out. 512 blocks x 256 thr; block = 16 rows.
// ---------------------------------------------------------------------------
__global__ __launch_bounds__(256) void proj_kernel(
    const float* __restrict__ AO, const float* __restrict__ w,
    const float* __restrict__ bias, float* __restrict__ out) {
  __shared__ float wct[DD * 68];  // column d at wct[d*68 + i]
  __shared__ float aol[256];      // aol[row_l*16 + h]
  __shared__ float bs[DD];
  const int t = threadIdx.x;
  const int b = blockIdx.x >> 7;  // 128 blocks per batch
  const int s_base = (blockIdx.x * 16) & (SS - 1);

  wct[(t & 15) * 68 + (t >> 4)] = w[t];
  if (t < DD) bs[t] = bias[t];
  {
    const int h = t >> 4, row_l = t & 15;
    const int bh = b * HH + h;
    aol[row_l * 16 + h] = AO[(size_t)bh * SS + s_base + row_l];
  }
  __syncthreads();

  const int row_l = t >> 4, d = t & 15;
  const float4* ao4 = (const float4*)aol;
  const float4* wc4 = (const float4*)wct;

  float y = bs[d];
#pragma unroll
  for (int g = 0; g < 4; ++g) {
    const float4 xv = ao4[row_l * 4 + g];
    const float4 wv = wc4[d * 17 + g];
    y = fmaf(xv.x, wv.x, y);
    y = fmaf(xv.y, wv.y, y);
    y = fmaf(xv.z, wv.z, y);
    y = fmaf(xv.w, wv.w, y);
  }
  out[(size_t)blockIdx.x * 256 + t] = y;
}

// ---------------------------------------------------------------------------
extern "C" void kernel_launch(void* const* d_in, const int* in_sizes, int n_in,
                              void* d_out, int out_size, void* d_ws,
                              size_t ws_size, hipStream_t stream) {
  const float* x = (const float*)d_in[0];       // [B,S,D]
  const float* w_qkv = (const float*)d_in[1];   // [D, 3D]
  const float* b_qkv = (const float*)d_in[2];   // [3D]
  const float* w_out = (const float*)d_in[3];   // [D, D]
  const float* b_out = (const float*)d_in[4];   // [D]
  float* out = (float*)d_out;                   // [B,S,D] fp32

  float* AO = (float*)d_ws;  // [64 bh][2048 s] attention out (512 KB)

  fused_attn_kernel<<<64, 1024, 0, stream>>>(x, w_qkv, b_qkv, AO);
  proj_kernel<<<512, 256, 0, stream>>>(AO, w_out, b_out, out);
}

// Round 3
// 73.405 us; speedup vs baseline: 1.0949x; 1.0573x over previous
//
#include <hip/hip_runtime.h>
#include <math.h>

// Problem constants (fixed by the reference).
#define BB 4
#define SS 2048
#define DD 16
#define HH 16
#define NM 32  // Taylor moments m = 0..31

#define EXP2(x) __builtin_amdgcn_exp2f(x)
#define LOG2E 1.44269504088896340736f

__constant__ float INVFACT[NM] = {
    1.000000000e+00f, 1.000000000e+00f, 5.000000000e-01f, 1.666666667e-01f,
    4.166666667e-02f, 8.333333333e-03f, 1.388888889e-03f, 1.984126984e-04f,
    2.480158730e-05f, 2.755731922e-06f, 2.755731922e-07f, 2.505210839e-08f,
    2.087675699e-09f, 1.605904384e-10f, 1.147074560e-11f, 7.647163732e-13f,
    4.779477332e-14f, 2.811457254e-15f, 1.561920697e-16f, 8.220635247e-18f,
    4.110317623e-19f, 1.957294106e-20f, 8.896791392e-22f, 3.868170171e-23f,
    1.611737571e-24f, 6.446950284e-26f, 2.479596263e-27f, 9.183689864e-29f,
    3.279889237e-30f, 1.130996289e-31f, 3.769987629e-33f, 1.216125042e-34f};

#define UNPACK16(X4, XR)                                                   \
  const float4 x0_ = (X4)[0], x1_ = (X4)[1], x2_ = (X4)[2], x3_ = (X4)[3]; \
  const float XR[16] = {x0_.x, x0_.y, x0_.z, x0_.w, x1_.x, x1_.y, x1_.z,   \
                        x1_.w, x2_.x, x2_.y, x2_.z, x2_.w, x3_.x, x3_.y,   \
                        x3_.z, x3_.w};

// ---------------------------------------------------------------------------
// Fused kernel, 4-way split: grid = 64 bh x 4 sub = 256 blocks x 1024 thr
// (one block per CU). Block (bh,sub) owns queries [sub*512, sub*512+512).
// Stage 1: k/v for rows [0, (sub+1)*512) -> LDS; q for own 512 rows.
// Stage 2: moment table SP[jb][m] = (sum_j k^m/m!, sum_j k^m v/m!) for
//          jb < (sub+1)*8; thread = (jb = t>>5, m = t&31).
// Stage 3: single-wave serial inclusive scan of SP over jb (2 barriers,
//          component-interleaved conflict-free addressing).
// Stage 4: 1 query/thread (t < 512): 32-term polynomial from SP[qb-1]
//          (wave-uniform broadcast) + exact exp2 diagonal block from LDS.
// Duplicated staging across subs is parallel slack on otherwise-idle CUs;
// critical block (sub=3) loses a stage-4 round and 8 barriers vs unsplit.
// ---------------------------------------------------------------------------
__global__ __launch_bounds__(1024) void fused_attn_kernel(
    const float* __restrict__ x, const float* __restrict__ w_qkv,
    const float* __restrict__ b_qkv, float* __restrict__ AO) {
  __shared__ float kl[SS];
  __shared__ float vl[SS];
  __shared__ float ql[512];
  __shared__ float2 SP[32 * 32];  // [jb][m], scanned inclusively over jb

  const int blk = blockIdx.x;
  const int sub = blk & 3;
  const int bh = blk >> 2;
  const int b = bh >> 4, h = bh & 15;
  const int t = threadIdx.x;
  const int R = (sub + 1) * 512;  // k/v rows needed
  const int NB = (sub + 1) * 8;   // jb blocks needed
  const int q0 = sub * 512;       // first owned query

  // Stage 1: k,v (and q for own range). Weights are block-uniform ->
  // scalar loads.
  {
    float wq[16], wk[16], wv[16];
#pragma unroll
    for (int i = 0; i < 16; ++i) {
      wq[i] = w_qkv[i * 48 + h];
      wk[i] = w_qkv[i * 48 + 16 + h];
      wv[i] = w_qkv[i * 48 + 32 + h];
    }
    const float bq = b_qkv[h], bk = b_qkv[16 + h], bv = b_qkv[32 + h];
    for (int r = 0; r * 1024 < R; ++r) {
      const int j = r * 1024 + t;
      if (j < R) {
        const float4* X4 = (const float4*)(x + ((size_t)b * SS + j) * DD);
        UNPACK16(X4, xr);
        float kk = bk, vv = bv;
#pragma unroll
        for (int i = 0; i < 16; ++i) {
          kk = fmaf(xr[i], wk[i], kk);
          vv = fmaf(xr[i], wv[i], vv);
        }
        kl[j] = kk;
        vl[j] = vv;
        if ((unsigned)(j - q0) < 512u) {  // wave-uniform (512-aligned)
          float qq = bq;
#pragma unroll
          for (int i = 0; i < 16; ++i) qq = fmaf(xr[i], wq[i], qq);
          ql[j - q0] = qq;
        }
      }
    }
  }
  __syncthreads();

  // Stage 2: moments. k^m via exp-by-squaring with per-lane bit selects.
  {
    const int m = t & 31;
    const int jb = t >> 5;  // 0..31
    if (jb < NB) {
      const float c = INVFACT[m];
      float s = 0.f, tv = 0.f;
      const int base = jb * 64;
      for (int u = 0; u < 64; ++u) {
        const float k = kl[base + u];  // 2-way broadcast (free)
        const float v = vl[base + u];
        const float k2 = k * k, k4 = k2 * k2, k8 = k4 * k4, k16 = k8 * k8;
        float p = (m & 1) ? k : 1.f;
        p *= (m & 2) ? k2 : 1.f;
        p *= (m & 4) ? k4 : 1.f;
        p *= (m & 8) ? k8 : 1.f;
        p *= (m & 16) ? k16 : 1.f;
        s += p;
        tv = fmaf(p, v, tv);
      }
      SP[t] = make_float2(s * c, tv * c);
    }
  }
  __syncthreads();

  // Stage 3: single-wave serial inclusive scan over jb. Lane l handles
  // component (l>>5) of moment m = l&31; addresses jb*64 + m*2 + comp are
  // all-distinct -> 2-way bank aliasing only (free).
  if (t < 64) {
    float* SPf = (float*)SP;
    const int off = ((t & 31) << 1) | (t >> 5);
    float run = 0.f;
    for (int jb = 0; jb < NB; ++jb) {
      run += SPf[jb * 64 + off];
      SPf[jb * 64 + off] = run;
    }
  }
  __syncthreads();

  // Stage 4: one query per thread (t < 512). Each wave covers exactly one
  // q-block -> SP row and diagonal kl/vl reads are wave-uniform broadcasts.
  if (t < 512) {
    const int i = q0 + t;
    const int lane = i & 63;
    const int qb = i >> 6;  // global q-block
    const float q = ql[t];
    const float qs = q * LOG2E;

    float num = 0.f, den = 0.f;
    if (qb > 0) {
      const float2* bc2 = SP + (size_t)(qb - 1) * 32;
      float p = 1.f;  // q^m
#pragma unroll
      for (int m = 0; m < NM; ++m) {
        const float2 st = bc2[m];  // broadcast read
        den = fmaf(p, st.x, den);
        num = fmaf(p, st.y, num);
        p *= q;
      }
    }

    // Exact diagonal block (lane-predicated: j_local <= lane).
    float ld = 0.f, ad = 0.f;
    const float4* kd4 = (const float4*)(kl + qb * 64);
    const float4* vd4 = (const float4*)(vl + qb * 64);
#pragma unroll
    for (int g = 0; g < 16; ++g) {
      const float4 k4 = kd4[g], v4 = vd4[g];
      const int jj = 4 * g;
      float e;
      e = EXP2(qs * k4.x); e = (jj + 0 <= lane) ? e : 0.f; ld += e; ad = fmaf(e, v4.x, ad);
      e = EXP2(qs * k4.y); e = (jj + 1 <= lane) ? e : 0.f; ld += e; ad = fmaf(e, v4.y, ad);
      e = EXP2(qs * k4.z); e = (jj + 2 <= lane) ? e : 0.f; ld += e; ad = fmaf(e, v4.z, ad);
      e = EXP2(qs * k4.w); e = (jj + 3 <= lane) ? e : 0.f; ld += e; ad = fmaf(e, v4.w, ad);
    }

    AO[(size_t)bh * SS + i] = (ad + num) / (ld + den);  // coalesced
  }
}

// ---------------------------------------------------------------------------
// Kernel C: out = AO @ w_out + b_out. 512 blocks x 256 thr; block = 16 rows.
// ---------------------------------------------------------------------------
__global__ __launch_bounds__(256) void proj_kernel(
    const float* __restrict__ AO, const float* __restrict__ w,
    const float* __restrict__ bias, float* __restrict__ out) {
  __shared__ float wct[DD * 68];  // column d at wct[d*68 + i]
  __shared__ float aol[256];      // aol[row_l*16 + h]
  __shared__ float bs[DD];
  const int t = threadIdx.x;
  const int b = blockIdx.x >> 7;  // 128 blocks per batch
  const int s_base = (blockIdx.x * 16) & (SS - 1);

  wct[(t & 15) * 68 + (t >> 4)] = w[t];
  if (t < DD) bs[t] = bias[t];
  {
    const int h = t >> 4, row_l = t & 15;
    const int bh = b * HH + h;
    aol[row_l * 16 + h] = AO[(size_t)bh * SS + s_base + row_l];
  }
  __syncthreads();

  const int row_l = t >> 4, d = t & 15;
  const float4* ao4 = (const float4*)aol;
  const float4* wc4 = (const float4*)wct;

  float y = bs[d];
#pragma unroll
  for (int g = 0; g < 4; ++g) {
    const float4 xv = ao4[row_l * 4 + g];
    const float4 wv = wc4[d * 17 + g];
    y = fmaf(xv.x, wv.x, y);
    y = fmaf(xv.y, wv.y, y);
    y = fmaf(xv.z, wv.z, y);
    y = fmaf(xv.w, wv.w, y);
  }
  out[(size_t)blockIdx.x * 256 + t] = y;
}

// ---------------------------------------------------------------------------
extern "C" void kernel_launch(void* const* d_in, const int* in_sizes, int n_in,
                              void* d_out, int out_size, void* d_ws,
                              size_t ws_size, hipStream_t stream) {
  const float* x = (const float*)d_in[0];       // [B,S,D]
  const float* w_qkv = (const float*)d_in[1];   // [D, 3D]
  const float* b_qkv = (const float*)d_in[2];   // [3D]
  const float* w_out = (const float*)d_in[3];   // [D, D]
  const float* b_out = (const float*)d_in[4];   // [D]
  float* out = (float*)d_out;                   // [B,S,D] fp32

  float* AO = (float*)d_ws;  // [64 bh][2048 s] attention out (512 KB)

  fused_attn_kernel<<<256, 1024, 0, stream>>>(x, w_qkv, b_qkv, AO);
  proj_kernel<<<512, 256, 0, stream>>>(AO, w_out, b_out, out);
}

// Round 4
// 70.934 us; speedup vs baseline: 1.1331x; 1.0348x over previous
//
#include <hip/hip_runtime.h>
#include <math.h>

// Problem constants (fixed by the reference).
#define BB 4
#define SS 2048
#define DD 16
#define HH 16
#define NM 32  // Taylor moments m = 0..31

#define EXP2(x) __builtin_amdgcn_exp2f(x)
#define LOG2E 1.44269504088896340736f

__constant__ float INVFACT[NM] = {
    1.000000000e+00f, 1.000000000e+00f, 5.000000000e-01f, 1.666666667e-01f,
    4.166666667e-02f, 8.333333333e-03f, 1.388888889e-03f, 1.984126984e-04f,
    2.480158730e-05f, 2.755731922e-06f, 2.755731922e-07f, 2.505210839e-08f,
    2.087675699e-09f, 1.605904384e-10f, 1.147074560e-11f, 7.647163732e-13f,
    4.779477332e-14f, 2.811457254e-15f, 1.561920697e-16f, 8.220635247e-18f,
    4.110317623e-19f, 1.957294106e-20f, 8.896791392e-22f, 3.868170171e-23f,
    1.611737571e-24f, 6.446950284e-26f, 2.479596263e-27f, 9.183689864e-29f,
    3.279889237e-30f, 1.130996289e-31f, 3.769987629e-33f, 1.216125042e-34f};

#define UNPACK16(X4, XR)                                                   \
  const float4 x0_ = (X4)[0], x1_ = (X4)[1], x2_ = (X4)[2], x3_ = (X4)[3]; \
  const float XR[16] = {x0_.x, x0_.y, x0_.z, x0_.w, x1_.x, x1_.y, x1_.z,   \
                        x1_.w, x2_.x, x2_.y, x2_.z, x2_.w, x3_.x, x3_.y,   \
                        x3_.z, x3_.w};

// ---------------------------------------------------------------------------
// Fused kernel, 4-way split: grid = 64 bh x 4 sub = 256 blocks x 1024 thr.
// Block (bh,sub) owns queries [sub*512, sub*512+512).
// Stage 1: k/v for rows [0, (sub+1)*512) -> LDS; q for own 512 rows.
// Stage 2: moment table SP[jb][m] = (sum_j k^m/m!, sum_j k^m v/m!).
//   Thread = (jb = t>>5, mg = (t>>2)&7, js = t&3): 4 consecutive moments
//   (m = 4mg..4mg+3) over 16 j's. Power chain p*=k amortizes k^m build to
//   ~5 VALU per (j,m) pair (was ~13). Partials reduced across the 4
//   j-slice lanes via shfl_xor(1), shfl_xor(2).
// Stage 3+4 fused, no serial scan: each stage-4 wave computes its OWN
//   prefix row (lane l sums SP component l over jb < qb, independent
//   pipelined reads), writes private PR[w], reads it back same-wave (no
//   barrier), then 32-term polynomial + exact exp2 diagonal block.
// 2 barriers total.
// ---------------------------------------------------------------------------
__global__ __launch_bounds__(1024) void fused_attn_kernel(
    const float* __restrict__ x, const float* __restrict__ w_qkv,
    const float* __restrict__ b_qkv, float* __restrict__ AO) {
  __shared__ float kl[SS];
  __shared__ float vl[SS];
  __shared__ float ql[512];
  __shared__ float2 SP[32 * 32];  // [jb][m] per-block moment sums (/m!)
  __shared__ float PR[8 * 64];    // per-wave prefix row (private to wave)

  const int blk = blockIdx.x;
  const int sub = blk & 3;
  const int bh = blk >> 2;
  const int b = bh >> 4, h = bh & 15;
  const int t = threadIdx.x;
  const int R = (sub + 1) * 512;  // k/v rows needed
  const int NB = (sub + 1) * 8;   // jb blocks needed
  const int q0 = sub * 512;       // first owned query

  // Stage 1: k,v (and q for own range). Weights are block-uniform ->
  // scalar loads.
  {
    float wq[16], wk[16], wv[16];
#pragma unroll
    for (int i = 0; i < 16; ++i) {
      wq[i] = w_qkv[i * 48 + h];
      wk[i] = w_qkv[i * 48 + 16 + h];
      wv[i] = w_qkv[i * 48 + 32 + h];
    }
    const float bq = b_qkv[h], bk = b_qkv[16 + h], bv = b_qkv[32 + h];
    for (int r = 0; r * 1024 < R; ++r) {
      const int j = r * 1024 + t;
      if (j < R) {
        const float4* X4 = (const float4*)(x + ((size_t)b * SS + j) * DD);
        UNPACK16(X4, xr);
        float kk = bk, vv = bv;
#pragma unroll
        for (int i = 0; i < 16; ++i) {
          kk = fmaf(xr[i], wk[i], kk);
          vv = fmaf(xr[i], wv[i], vv);
        }
        kl[j] = kk;
        vl[j] = vv;
        if ((unsigned)(j - q0) < 512u) {  // wave-uniform (512-aligned)
          float qq = bq;
#pragma unroll
          for (int i = 0; i < 16; ++i) qq = fmaf(xr[i], wq[i], qq);
          ql[j - q0] = qq;
        }
      }
    }
  }
  __syncthreads();

  // Stage 2: moments, 4 m's per thread via power chain.
  {
    const int jb = t >> 5;        // 0..31
    const int mg = (t >> 2) & 7;  // moment group: m = 4mg..4mg+3
    const int js = t & 3;         // j-slice (16 j's, float4-interleaved)
    if (jb < NB) {
      float s0 = 0.f, s1 = 0.f, s2 = 0.f, s3 = 0.f;
      float w0 = 0.f, w1 = 0.f, w2 = 0.f, w3 = 0.f;
      const float4* kp = (const float4*)(kl + jb * 64);
      const float4* vp = (const float4*)(vl + jb * 64);
#pragma unroll
      for (int u = 0; u < 4; ++u) {
        const float4 kk = kp[u * 4 + js];  // 4 bank-quads x 2-way: free
        const float4 vv = vp[u * 4 + js];
        const float ke[4] = {kk.x, kk.y, kk.z, kk.w};
        const float ve[4] = {vv.x, vv.y, vv.z, vv.w};
#pragma unroll
        for (int e = 0; e < 4; ++e) {
          const float k = ke[e], v = ve[e];
          const float k2 = k * k, k4 = k2 * k2, k8 = k4 * k4, k16 = k8 * k8;
          float p = (mg & 1) ? k4 : 1.f;  // masks loop-invariant (hoisted)
          p *= (mg & 2) ? k8 : 1.f;
          p *= (mg & 4) ? k16 : 1.f;      // p = k^(4*mg)
          s0 += p; w0 = fmaf(p, v, w0);
          p *= k;
          s1 += p; w1 = fmaf(p, v, w1);
          p *= k;
          s2 += p; w2 = fmaf(p, v, w2);
          p *= k;
          s3 += p; w3 = fmaf(p, v, w3);
        }
      }
      // Reduce the 4 j-slice lanes (bits 0-1 of t) -> all lanes hold sums.
      s0 += __shfl_xor(s0, 1); s0 += __shfl_xor(s0, 2);
      s1 += __shfl_xor(s1, 1); s1 += __shfl_xor(s1, 2);
      s2 += __shfl_xor(s2, 1); s2 += __shfl_xor(s2, 2);
      s3 += __shfl_xor(s3, 1); s3 += __shfl_xor(s3, 2);
      w0 += __shfl_xor(w0, 1); w0 += __shfl_xor(w0, 2);
      w1 += __shfl_xor(w1, 1); w1 += __shfl_xor(w1, 2);
      w2 += __shfl_xor(w2, 1); w2 += __shfl_xor(w2, 2);
      w3 += __shfl_xor(w3, 1); w3 += __shfl_xor(w3, 2);
      // Lane js writes moment m = 4mg + js.
      const int m = mg * 4 + js;
      const float c = INVFACT[m];
      const float ss = (js == 0) ? s0 : (js == 1) ? s1 : (js == 2) ? s2 : s3;
      const float tt = (js == 0) ? w0 : (js == 1) ? w1 : (js == 2) ? w2 : w3;
      SP[jb * 32 + m] = make_float2(ss * c, tt * c);
    }
  }
  __syncthreads();

  // Stage 3+4: per-wave prefix row, then attention. One query per thread
  // (t < 512); each wave covers exactly one q-block -> PR row and diagonal
  // kl/vl reads are wave-uniform broadcasts.
  if (t < 512) {
    const int l = t & 63;
    const int w = t >> 6;
    const int qb = (q0 >> 6) + w;  // this wave's global q-block

    // Prefix over full blocks jb < qb; lane l owns float component l
    // (banks 2-way aliased across lanes: free). Reads independent ->
    // pipelined. Written to this wave's private PR row; read back below
    // same-wave (lgkmcnt ordering, no barrier needed).
    {
      const float* SPf = (const float*)SP;
      float run = 0.f;
      for (int jb = 0; jb < qb; ++jb) run += SPf[jb * 64 + l];
      PR[w * 64 + l] = run;
    }

    const int i = q0 + t;
    const float q = ql[t];
    const float qs = q * LOG2E;

    // 32-term polynomial from this wave's prefix row (broadcast b128
    // reads; zero row when qb == 0 contributes nothing).
    float num = 0.f, den = 0.f;
    {
      const float4* bc4 = (const float4*)(PR + w * 64);
      float p = 1.f;  // q^m
#pragma unroll
      for (int g = 0; g < 16; ++g) {
        const float4 st = bc4[g];  // (S_2g, T_2g, S_2g+1, T_2g+1)
        den = fmaf(p, st.x, den);
        num = fmaf(p, st.y, num);
        p *= q;
        den = fmaf(p, st.z, den);
        num = fmaf(p, st.w, num);
        p *= q;
      }
    }

    // Exact diagonal block (lane-predicated: j_local <= lane).
    float ld = 0.f, ad = 0.f;
    const float4* kd4 = (const float4*)(kl + qb * 64);
    const float4* vd4 = (const float4*)(vl + qb * 64);
#pragma unroll
    for (int g = 0; g < 16; ++g) {
      const float4 k4 = kd4[g], v4 = vd4[g];
      const int jj = 4 * g;
      float e;
      e = EXP2(qs * k4.x); e = (jj + 0 <= l) ? e : 0.f; ld += e; ad = fmaf(e, v4.x, ad);
      e = EXP2(qs * k4.y); e = (jj + 1 <= l) ? e : 0.f; ld += e; ad = fmaf(e, v4.y, ad);
      e = EXP2(qs * k4.z); e = (jj + 2 <= l) ? e : 0.f; ld += e; ad = fmaf(e, v4.z, ad);
      e = EXP2(qs * k4.w); e = (jj + 3 <= l) ? e : 0.f; ld += e; ad = fmaf(e, v4.w, ad);
    }

    AO[(size_t)bh * SS + i] = (ad + num) / (ld + den);  // coalesced
  }
}

// ---------------------------------------------------------------------------
// Kernel C: out = AO @ w_out + b_out. 512 blocks x 256 thr; block = 16 rows.
// ---------------------------------------------------------------------------
__global__ __launch_bounds__(256) void proj_kernel(
    const float* __restrict__ AO, const float* __restrict__ w,
    const float* __restrict__ bias, float* __restrict__ out) {
  __shared__ float wct[DD * 68];  // column d at wct[d*68 + i]
  __shared__ float aol[256];      // aol[row_l*16 + h]
  __shared__ float bs[DD];
  const int t = threadIdx.x;
  const int b = blockIdx.x >> 7;  // 128 blocks per batch
  const int s_base = (blockIdx.x * 16) & (SS - 1);

  wct[(t & 15) * 68 + (t >> 4)] = w[t];
  if (t < DD) bs[t] = bias[t];
  {
    const int h = t >> 4, row_l = t & 15;
    const int bh = b * HH + h;
    aol[row_l * 16 + h] = AO[(size_t)bh * SS + s_base + row_l];
  }
  __syncthreads();

  const int row_l = t >> 4, d = t & 15;
  const float4* ao4 = (const float4*)aol;
  const float4* wc4 = (const float4*)wct;

  float y = bs[d];
#pragma unroll
  for (int g = 0; g < 4; ++g) {
    const float4 xv = ao4[row_l * 4 + g];
    const float4 wv = wc4[d * 17 + g];
    y = fmaf(xv.x, wv.x, y);
    y = fmaf(xv.y, wv.y, y);
    y = fmaf(xv.z, wv.z, y);
    y = fmaf(xv.w, wv.w, y);
  }
  out[(size_t)blockIdx.x * 256 + t] = y;
}

// ---------------------------------------------------------------------------
extern "C" void kernel_launch(void* const* d_in, const int* in_sizes, int n_in,
                              void* d_out, int out_size, void* d_ws,
                              size_t ws_size, hipStream_t stream) {
  const float* x = (const float*)d_in[0];       // [B,S,D]
  const float* w_qkv = (const float*)d_in[1];   // [D, 3D]
  const float* b_qkv = (const float*)d_in[2];   // [3D]
  const float* w_out = (const float*)d_in[3];   // [D, D]
  const float* b_out = (const float*)d_in[4];   // [D]
  float* out = (float*)d_out;                   // [B,S,D] fp32

  float* AO = (float*)d_ws;  // [64 bh][2048 s] attention out (512 KB)

  fused_attn_kernel<<<256, 1024, 0, stream>>>(x, w_qkv, b_qkv, AO);
  proj_kernel<<<512, 256, 0, stream>>>(AO, w_out, b_out, out);
}